// Round 7
// baseline (182.685 us; speedup 1.0000x reference)
//
#include <hip/hip_runtime.h>
#include <math.h>

#define N 16384
#define F 256
#define K_KEEP 8192
#define JCH 512    // j-chunk length for rank kernel
#define IPT 4      // i per thread in rank kernel
#define QS 4096    // columns per apool block (4 waves x 1024-col slices)
#define SLICE 1024 // columns per wave slice
#define APOOL_BLOCKS (K_KEEP * 4)

typedef float f32x4 __attribute__((ext_vector_type(4)));  // native vec for nontemporal builtins

// ---------------------------------------------------------------------------
// Kernel 1: y[i] = dot(X[i,:], p)/||p|| (fp64 accum) + monotone u64 sort key.
// One wave per row; lane l covers 4 consecutive floats.
// ---------------------------------------------------------------------------
__global__ __launch_bounds__(256) void score_kernel(const float* __restrict__ X,
                                                    const float* __restrict__ p,
                                                    double* __restrict__ y,
                                                    unsigned long long* __restrict__ key) {
    const int wave = threadIdx.x >> 6;
    const int lane = threadIdx.x & 63;
    const int row  = blockIdx.x * 4 + wave;

    const float4 pv = *reinterpret_cast<const float4*>(p + lane * 4);
    const float4 xv = *reinterpret_cast<const float4*>(X + (size_t)row * F + lane * 4);

    double pp = (double)pv.x * pv.x + (double)pv.y * pv.y +
                (double)pv.z * pv.z + (double)pv.w * pv.w;
    double xp = (double)xv.x * pv.x + (double)xv.y * pv.y +
                (double)xv.z * pv.z + (double)xv.w * pv.w;

    #pragma unroll
    for (int off = 32; off >= 1; off >>= 1) {
        pp += __shfl_down(pp, off, 64);
        xp += __shfl_down(xp, off, 64);
    }
    if (lane == 0) {
        const double yy = xp / sqrt(pp);
        y[row] = yy;
        const long long b = __double_as_longlong(yy);
        key[row] = (unsigned long long)b ^
                   ((b < 0) ? 0xFFFFFFFFFFFFFFFFULL : 0x8000000000000000ULL);
    }
}

// ---------------------------------------------------------------------------
// Kernel 2: partial ranks. IPT=4 i-values per thread amortize each LDS read
// over 4 compares; b128 reads fetch 2 keys per LDS instruction. Keys are
// distinct doubles, so strict u64 > is the exact top_k order.
// ---------------------------------------------------------------------------
__global__ __launch_bounds__(256) void rank_kernel(const unsigned long long* __restrict__ key,
                                                   unsigned short* __restrict__ rankp) {
    __shared__ ulonglong2 kch2[JCH / 2];   // 4 KB
    const int t     = threadIdx.x;
    const int jc    = blockIdx.y;
    const int jbase = jc * JCH;
    kch2[t] = *reinterpret_cast<const ulonglong2*>(key + jbase + 2 * t);
    __syncthreads();

    const int ibase = blockIdx.x * (256 * IPT) + t;
    const unsigned long long k0 = key[ibase];
    const unsigned long long k1 = key[ibase + 256];
    const unsigned long long k2 = key[ibase + 512];
    const unsigned long long k3 = key[ibase + 768];
    int c0 = 0, c1 = 0, c2 = 0, c3 = 0;
    #pragma unroll 8
    for (int jj = 0; jj < JCH / 2; ++jj) {
        const ulonglong2 kk = kch2[jj];
        c0 += (int)(kk.x > k0) + (int)(kk.y > k0);
        c1 += (int)(kk.x > k1) + (int)(kk.y > k1);
        c2 += (int)(kk.x > k2) + (int)(kk.y > k2);
        c3 += (int)(kk.x > k3) + (int)(kk.y > k3);
    }
    rankp[jc * N + ibase      ] = (unsigned short)c0;
    rankp[jc * N + ibase + 256] = (unsigned short)c1;
    rankp[jc * N + ibase + 512] = (unsigned short)c2;
    rankp[jc * N + ibase + 768] = (unsigned short)c3;
}

// ---------------------------------------------------------------------------
// Kernel 3: total rank -> kept flags (64-bit words).
// ---------------------------------------------------------------------------
__global__ __launch_bounds__(256) void flags_kernel(const unsigned short* __restrict__ rankp,
                                                    unsigned long long* __restrict__ flagbits) {
    const int i = blockIdx.x * 256 + threadIdx.x; // coalesced
    int r = 0;
    #pragma unroll
    for (int jc = 0; jc < N / JCH; ++jc) r += (int)rankp[jc * N + i];
    const bool kept = (r < K_KEEP);
    const unsigned long long m = __ballot(kept);
    if ((threadIdx.x & 63) == 0) flagbits[i >> 6] = m;
}

// ---------------------------------------------------------------------------
// Kernel 4 (single block): popcount+scan the 256 flag words -> wexcl[256];
// emit ascending kept indices idx[] and in-slice u16 source offsets srcq[].
// ---------------------------------------------------------------------------
__global__ __launch_bounds__(256) void emit_kernel(const unsigned long long* __restrict__ flagbits,
                                                   int* __restrict__ idx,
                                                   unsigned short* __restrict__ srcq,
                                                   int* __restrict__ wexcl) {
    __shared__ int sc[256];
    const int t = threadIdx.x;
    const unsigned long long m = flagbits[t];
    const int c = __popcll(m);
    sc[t] = c;
    __syncthreads();
    for (int off = 1; off < 256; off <<= 1) {
        const int v = (t >= off) ? sc[t - off] : 0;
        __syncthreads();
        sc[t] += v;
        __syncthreads();
    }
    const int excl = sc[t] - c;
    wexcl[t] = excl;

    int base = excl;
    unsigned long long mm = m;
    const int col = t * 64;
    while (mm) {
        const int b = __ffsll((long long)mm) - 1;
        mm &= (mm - 1);
        const int i = col + b;
        idx[base]  = i;
        srcq[base] = (unsigned short)(i & (SLICE - 1));
        ++base;
    }
}

// ---------------------------------------------------------------------------
// Kernel 5 (fused pool): blocks [0, 32768): A_pooled. Each WAVE owns one
// 1024-col slice: stage slice into its own LDS region (ds_write_b128),
// then gather its own output range via srcq — barrier-free, 32 self-paced
// streaming waves per CU. Blocks [32768, +2048): X_pooled.
// ---------------------------------------------------------------------------
__global__ __launch_bounds__(256) void pool_kernel(const float* __restrict__ A,
                                                   const float* __restrict__ X,
                                                   const double* __restrict__ y,
                                                   const int* __restrict__ idx,
                                                   const unsigned short* __restrict__ srcq,
                                                   const int* __restrict__ wexcl,
                                                   float* __restrict__ outX,
                                                   float* __restrict__ outA) {
    const int t = threadIdx.x;

    if (blockIdx.x >= APOOL_BLOCKS) {  // ---- xpool part ----
        const int k    = (blockIdx.x - APOOL_BLOCKS) * 4 + (t >> 6);
        const int lane = t & 63;
        const int src  = idx[k];
        const float tf = tanhf((float)y[src]);
        const float4 xv = *reinterpret_cast<const float4*>(X + (size_t)src * F + lane * 4);
        float4 o = {xv.x * tf, xv.y * tf, xv.z * tf, xv.w * tf};
        *reinterpret_cast<float4*>(outX + (size_t)k * F + lane * 4) = o;
        return;
    }

    // ---- apool part: one (row, quarter) per block; one slice per wave ----
    __shared__ float buf[QS];
    const int row  = blockIdx.x >> 2;
    const int h    = blockIdx.x & 3;
    const int wv   = t >> 6;
    const int lane = t & 63;
    const int s    = h * 4 + wv;                 // slice id 0..15
    const int ridx = idx[row];                   // uniform
    const int kb   = wexcl[s * 16];              // wave-uniform
    const int ke   = (s < 15) ? wexcl[s * 16 + 16] : K_KEEP;

    const f32x4* __restrict__ a4 =
        reinterpret_cast<const f32x4*>(A + (size_t)ridx * N + s * SLICE);
    f32x4* __restrict__ b4 = reinterpret_cast<f32x4*>(buf + wv * SLICE);
    #pragma unroll
    for (int q = 0; q < 4; ++q)
        b4[q * 64 + lane] = __builtin_nontemporal_load(a4 + q * 64 + lane);
    // no barrier: wave-local dependency, compiler inserts the lgkmcnt wait

    const float* __restrict__ wbuf = buf + wv * SLICE;
    float* __restrict__ orow = outA + (size_t)row * K_KEEP;
    const int k4b = (kb + 3) & ~3;
    const int k4e = ke & ~3;
    if (lane < (k4b - kb) && kb + lane < ke) orow[kb + lane] = wbuf[srcq[kb + lane]];
    if (lane < (ke - k4e) && k4e + lane >= kb) orow[k4e + lane] = wbuf[srcq[k4e + lane]];
    for (int k4 = k4b + 4 * lane; k4 < k4e; k4 += 256) {
        const ushort4 s4 = *reinterpret_cast<const ushort4*>(srcq + k4);
        f32x4 v = {wbuf[s4.x], wbuf[s4.y], wbuf[s4.z], wbuf[s4.w]};
        __builtin_nontemporal_store(v, reinterpret_cast<f32x4*>(orow + k4));
    }
}

// ---------------------------------------------------------------------------
extern "C" void kernel_launch(void* const* d_in, const int* in_sizes, int n_in,
                              void* d_out, int out_size, void* d_ws, size_t ws_size,
                              hipStream_t stream) {
    const float* X = (const float*)d_in[0];  // [N, F]
    const float* A = (const float*)d_in[1];  // [N, N]
    const float* p = (const float*)d_in[2];  // [F, 1]

    float* out  = (float*)d_out;
    float* outX = out;                          // [K_KEEP, F]
    float* outA = out + (size_t)K_KEEP * F;     // [K_KEEP, K_KEEP]

    char* ws = (char*)d_ws;
    double*             y        = (double*)ws;                           // 131072 B
    unsigned long long* key      = (unsigned long long*)(ws + 131072);    // 131072 B
    unsigned short*     rankp    = (unsigned short*)(ws + 262144);        // 32*N*2 = 1048576 B
    unsigned long long* flagbits = (unsigned long long*)(ws + 1310720);   // 2048 B
    int*                wexcl    = (int*)(ws + 1312768);                  // 1024 B
    int*                idx      = (int*)(ws + 1313792);                  // 32768 B
    unsigned short*     srcq     = (unsigned short*)(ws + 1346560);       // 16384 B

    score_kernel<<<N / 4, 256, 0, stream>>>(X, p, y, key);
    rank_kernel<<<dim3(N / (256 * IPT), N / JCH), 256, 0, stream>>>(key, rankp);
    flags_kernel<<<N / 256, 256, 0, stream>>>(rankp, flagbits);
    emit_kernel<<<1, 256, 0, stream>>>(flagbits, idx, srcq, wexcl);
    pool_kernel<<<APOOL_BLOCKS + K_KEEP / 4, 256, 0, stream>>>(A, X, y, idx, srcq, wexcl,
                                                               outX, outA);
}